// Round 15
// baseline (255.503 us; speedup 1.0000x reference)
//
#include <hip/hip_runtime.h>

#define NN 100000      // nodes
#define NE 1600000     // edges
#define DD 128         // input dim (elements per row)
#define MD 512         // mlp dim = 128*4
#define SEL 16384      // senders count
#define MROWS 32768    // senders + receivers rows
#define NBKT 196       // buckets of 512 nodes
#define TILE 4096      // edges per k_binA block
#define SEGCAP 16384   // per-bucket ebuf slot capacity
#define CSTRIDE 12288  // per-bucket padded CSR capacity (mean ~9984)
#define NBINA ((NE + TILE - 1) / TILE)   // 391
#define NMARK ((2 * SEL + 255) / 256)    // 128
#define NCOMP ((NN + 255) / 256)         // 391

typedef __attribute__((ext_vector_type(8))) short bf16x8;
typedef __attribute__((ext_vector_type(4))) float f32x4;

__device__ __forceinline__ unsigned short f2bf(float f) {
  unsigned u = __float_as_uint(f);
  u += 0x7fff + ((u >> 16) & 1);   // round-to-nearest-even
  return (unsigned short)(u >> 16);
}
__device__ __forceinline__ float bflo(unsigned v) { return __uint_as_float(v << 16); }
__device__ __forceinline__ float bfhi(unsigned v) { return __uint_as_float(v & 0xffff0000u); }

// ---- bin edges into strided ebuf slices; tail blocks do the mark pass ----
__global__ __launch_bounds__(256) void k_binA_mark(const int* __restrict__ src,
                                                   const int* __restrict__ dst,
                                                   int* __restrict__ gcursor,
                                                   unsigned* __restrict__ ebuf,
                                                   const int* __restrict__ sl,
                                                   const int* __restrict__ rl,
                                                   int* __restrict__ mark) {
  if (blockIdx.x >= NBINA) {  // mark tail
    const int i = (blockIdx.x - NBINA) * 256 + threadIdx.x;
    if (i < SEL) mark[sl[i]] = 1;
    else if (i < 2 * SEL) mark[rl[i - SEL]] = 1;
    return;
  }
  __shared__ int hist[NBKT];
  __shared__ int base[NBKT];
  __shared__ int cnt2[NBKT];
  const int tid = threadIdx.x;
  const long e0 = (long)blockIdx.x * TILE;
  for (int i = tid; i < NBKT; i += 256) { hist[i] = 0; cnt2[i] = 0; }
  __syncthreads();
  unsigned pk[16]; int bk[16];
  #pragma unroll
  for (int k = 0; k < 16; ++k) {
    const long e = e0 + k * 256 + tid;
    bk[k] = -1;
    if (e < NE) {
      const int d = dst[e], s = src[e];
      bk[k] = d >> 9;
      pk[k] = ((unsigned)s << 9) | (unsigned)(d & 511);
      atomicAdd(&hist[bk[k]], 1);
    }
  }
  __syncthreads();
  for (int i = tid; i < NBKT; i += 256)
    base[i] = i * SEGCAP + atomicAdd(&gcursor[i], hist[i]);
  __syncthreads();
  #pragma unroll
  for (int k = 0; k < 16; ++k) {
    if (bk[k] >= 0) {
      const int lp = atomicAdd(&cnt2[bk[k]], 1);
      ebuf[base[bk[k]] + lp] = pk[k];
    }
  }
}

// ---- fused: per-bucket degree+dinv+scan + LDS scatter -> fixed-stride CSR ----
__global__ __launch_bounds__(256) void k_degbinB(const unsigned* __restrict__ ebuf,
                                                 const int* __restrict__ bcnt,
                                                 float* __restrict__ dinv,
                                                 int4* __restrict__ nodeinfo,
                                                 int* __restrict__ csr,
                                                 unsigned short* __restrict__ x0,
                                                 unsigned short* __restrict__ x1,
                                                 unsigned short* __restrict__ x2,
                                                 const int* __restrict__ mark,
                                                 int* __restrict__ list,
                                                 int* __restrict__ lcnt,
                                                 int* __restrict__ uidx) {
  if (blockIdx.x >= NBKT) {  // compact tail (mark completed last kernel)
    const int n = (blockIdx.x - NBKT) * 256 + threadIdx.x;
    if (n < NN && mark[n]) {
      const int p = atomicAdd(lcnt, 1);
      list[p] = n;
      uidx[n] = p;
    }
    return;
  }
  __shared__ int ld[512];
  __shared__ int ps[256];
  __shared__ int rs[512];
  __shared__ int cnt[512];
  __shared__ int seg[CSTRIDE];
  const int b = blockIdx.x;
  const int n0 = b << 9;
  const int nn = min(512, NN - n0);
  const int tid = threadIdx.x;
  for (int i = tid; i < 512; i += 256) ld[i] = 0;
  __syncthreads();
  const int s0 = b * SEGCAP;
  const int c = bcnt[b];
  for (int i = tid; i < c; i += 256) atomicAdd(&ld[ebuf[s0 + i] & 511], 1);
  __syncthreads();
  const int d0 = (tid * 2 < nn) ? ld[tid * 2] : 0;
  const int d1 = (tid * 2 + 1 < nn) ? ld[tid * 2 + 1] : 0;
  const int p0 = (d0 + 7) & ~7, p1 = (d1 + 7) & ~7;
  ps[tid] = p0 + p1;
  __syncthreads();
  for (int o = 1; o < 256; o <<= 1) {
    int t2 = (tid >= o) ? ps[tid - o] : 0;
    __syncthreads();
    ps[tid] += t2;
    __syncthreads();
  }
  const int exbase = ps[tid] - (p0 + p1);
  const int cb = b * CSTRIDE;
  if (tid * 2 < nn) {
    const float dv = rsqrtf(fmaxf((float)d0, 1.f));
    dinv[n0 + tid * 2] = dv;
    rs[tid * 2] = exbase;
    nodeinfo[n0 + tid * 2] = make_int4(cb + exbase, p0, __float_as_int(dv * dv), 0);
  }
  if (tid * 2 + 1 < nn) {
    const float dv = rsqrtf(fmaxf((float)d1, 1.f));
    dinv[n0 + tid * 2 + 1] = dv;
    rs[tid * 2 + 1] = exbase + p0;
    nodeinfo[n0 + tid * 2 + 1] = make_int4(cb + exbase + p0, p1, __float_as_int(dv * dv), 0);
  }
  const int padtot = ps[255];
  for (int i = tid; i < nn; i += 256) cnt[i] = 0;
  for (int i = tid; i < padtot; i += 256) seg[i] = NN << 8;  // sentinel pad
  __syncthreads();
  for (int i = tid; i < c; i += 256) {
    const unsigned e = ebuf[s0 + i];
    const int dl = e & 511;
    const int pos = rs[dl] + atomicAdd(&cnt[dl], 1);
    seg[pos] = (int)((e >> 9) << 8);   // byte offset of src row (256 B rows)
  }
  __syncthreads();
  for (int i = tid; i < padtot; i += 256) csr[cb + i] = seg[i];
  if (b == 0 && tid < 64) {  // zero the sentinel row NN of each x buffer
    ((unsigned*)(x0 + (size_t)NN * DD))[tid] = 0u;
    ((unsigned*)(x1 + (size_t)NN * DD))[tid] = 0u;
    ((unsigned*)(x2 + (size_t)NN * DD))[tid] = 0u;
  }
}

// ---- feature-split aggregation: wave = 2 (node,half) pairs x2 interleave ----
// Half h handled only by blocks with (bid&7)>>2 == h (XCD-affinity heuristic).
// Two independent node-pairs per wave iteration -> 16 gathers in flight.
__global__ __launch_bounds__(256) void k_aggs(const int4* __restrict__ nodeinfo,
                                              const int* __restrict__ csr,
                                              const unsigned short* __restrict__ xin,
                                              unsigned short* __restrict__ xout) {
  const int lane = threadIdx.x & 63;
  const int hi = lane >> 5, l5 = lane & 31;
  const int bid = blockIdx.x;
  const int xcd = bid & 7;
  const int h = xcd >> 2;                       // feature half
  const int g = (bid >> 3) * 4 + (xcd & 3);     // block index within half-group
  const int wvh = g * 4 + (threadIdx.x >> 6);   // wave index within half-group
  const int stride = gridDim.x * 2;             // waves per half-group
  const char* xb = (const char*)xin;
  const unsigned lc = (unsigned)(h * 128 + l5 * 4);  // byte offset within row
  for (int p = wvh; 2 * p < NN; p += 2 * stride) {
    const int idxA = 2 * p + hi;                // NN even -> idxA < NN
    const int pB = p + stride;
    const bool doBitem = 2 * pB < NN;
    const int idxB = 2 * pB + hi;
    const int4 niA = nodeinfo[idxA];
    const int4 niB = nodeinfo[doBitem ? idxB : idxA];
    const int cA = niA.y;
    const int cB = doBitem ? niB.y : 0;
    float axA[4] = {}, ayA[4] = {}, axB[4] = {}, ayB[4] = {};
    int4 a0, a1, b0, b1;
    if (cA > 0) { a0 = *(const int4*)(csr + niA.x); a1 = *(const int4*)(csr + niA.x + 4); }
    if (cB > 0) { b0 = *(const int4*)(csr + niB.x); b1 = *(const int4*)(csr + niB.x + 4); }
    const int cmax = max(cA, cB);
    for (int j = 0; j < cmax; j += 8) {
      const bool dA = j < cA, dB = j < cB;
      const int4 fa0 = a0, fa1 = a1, fb0 = b0, fb1 = b1;
      unsigned vA[8], vB[8];
      if (dA) {
        vA[0] = *(const unsigned*)(xb + ((unsigned)fa0.x + lc));
        vA[1] = *(const unsigned*)(xb + ((unsigned)fa0.y + lc));
        vA[2] = *(const unsigned*)(xb + ((unsigned)fa0.z + lc));
        vA[3] = *(const unsigned*)(xb + ((unsigned)fa0.w + lc));
        vA[4] = *(const unsigned*)(xb + ((unsigned)fa1.x + lc));
        vA[5] = *(const unsigned*)(xb + ((unsigned)fa1.y + lc));
        vA[6] = *(const unsigned*)(xb + ((unsigned)fa1.z + lc));
        vA[7] = *(const unsigned*)(xb + ((unsigned)fa1.w + lc));
      }
      if (dB) {
        vB[0] = *(const unsigned*)(xb + ((unsigned)fb0.x + lc));
        vB[1] = *(const unsigned*)(xb + ((unsigned)fb0.y + lc));
        vB[2] = *(const unsigned*)(xb + ((unsigned)fb0.z + lc));
        vB[3] = *(const unsigned*)(xb + ((unsigned)fb0.w + lc));
        vB[4] = *(const unsigned*)(xb + ((unsigned)fb1.x + lc));
        vB[5] = *(const unsigned*)(xb + ((unsigned)fb1.y + lc));
        vB[6] = *(const unsigned*)(xb + ((unsigned)fb1.z + lc));
        vB[7] = *(const unsigned*)(xb + ((unsigned)fb1.w + lc));
      }
      if (j + 8 < cA) {  // prefetch next csr quads
        a0 = *(const int4*)(csr + niA.x + j + 8);
        a1 = *(const int4*)(csr + niA.x + j + 12);
      }
      if (j + 8 < cB) {
        b0 = *(const int4*)(csr + niB.x + j + 8);
        b1 = *(const int4*)(csr + niB.x + j + 12);
      }
      if (dA) {
        #pragma unroll
        for (int u = 0; u < 8; ++u) { axA[u & 3] += bflo(vA[u]); ayA[u & 3] += bfhi(vA[u]); }
      }
      if (dB) {
        #pragma unroll
        for (int u = 0; u < 8; ++u) { axB[u & 3] += bflo(vB[u]); ayB[u & 3] += bfhi(vB[u]); }
      }
    }
    {
      const float s = __int_as_float(niA.z);
      const float rx = ((axA[0] + axA[1]) + (axA[2] + axA[3])) * s;
      const float ry = ((ayA[0] + ayA[1]) + (ayA[2] + ayA[3])) * s;
      *(unsigned*)((char*)xout + ((unsigned)idxA << 8) + lc) =
          ((unsigned)f2bf(ry) << 16) | f2bf(rx);
    }
    if (doBitem) {
      const float s = __int_as_float(niB.z);
      const float rx = ((axB[0] + axB[1]) + (axB[2] + axB[3])) * s;
      const float ry = ((ayB[0] + ayB[1]) + (ayB[2] + ayB[3])) * s;
      *(unsigned*)((char*)xout + ((unsigned)idxB << 8) + lc) =
          ((unsigned)f2bf(ry) << 16) | f2bf(rx);
    }
  }
}

// ---- layer-3 aggregation (listed nodes, full row) + all four z-slices ----
__global__ __launch_bounds__(256) void k_agg3z(const int4* __restrict__ nodeinfo,
                                               const int* __restrict__ csr,
                                               const unsigned short* __restrict__ x0,
                                               const unsigned short* __restrict__ x1,
                                               const unsigned short* __restrict__ x2,
                                               unsigned short* __restrict__ zbuf,
                                               const int* __restrict__ list,
                                               const int* __restrict__ lcnt) {
  const int lane = threadIdx.x & 63;
  const int wv = (blockIdx.x * blockDim.x + threadIdx.x) >> 6;
  const int nw = (gridDim.x * blockDim.x) >> 6;
  const int cl = *lcnt;
  const char* xb2 = (const char*)x2;
  const unsigned lc = (unsigned)(lane * 4);
  int r = wv;
  if (r >= cl) return;
  int nln = list[r];
  for (; r < cl; r += nw) {
    const int n = nln;
    const int rn = r + nw;
    if (rn < cl) nln = list[rn];  // prefetch next list entry
    const int4 ni = nodeinfo[n];
    const int start = ni.x;
    const int cntp = ni.y;
    float ax[8], ay[8];
    #pragma unroll
    for (int u = 0; u < 8; ++u) { ax[u] = 0.f; ay[u] = 0.f; }
    int4 e0 = *(const int4*)(csr + start);
    int4 e1 = *(const int4*)(csr + start + 4);
    for (int j = 0; j < cntp; j += 8) {
      const int4 f0 = e0, f1 = e1;
      if (j + 8 < cntp) {
        e0 = *(const int4*)(csr + start + j + 8);
        e1 = *(const int4*)(csr + start + j + 12);
      }
      unsigned v[8];
      v[0] = *(const unsigned*)(xb2 + ((unsigned)f0.x + lc));
      v[1] = *(const unsigned*)(xb2 + ((unsigned)f0.y + lc));
      v[2] = *(const unsigned*)(xb2 + ((unsigned)f0.z + lc));
      v[3] = *(const unsigned*)(xb2 + ((unsigned)f0.w + lc));
      v[4] = *(const unsigned*)(xb2 + ((unsigned)f1.x + lc));
      v[5] = *(const unsigned*)(xb2 + ((unsigned)f1.y + lc));
      v[6] = *(const unsigned*)(xb2 + ((unsigned)f1.z + lc));
      v[7] = *(const unsigned*)(xb2 + ((unsigned)f1.w + lc));
      #pragma unroll
      for (int u = 0; u < 8; ++u) { ax[u] += bflo(v[u]); ay[u] += bfhi(v[u]); }
    }
    const float s = __int_as_float(ni.z);
    const float rx = (((ax[0] + ax[1]) + (ax[2] + ax[3])) + ((ax[4] + ax[5]) + (ax[6] + ax[7]))) * s;
    const float ry = (((ay[0] + ay[1]) + (ay[2] + ay[3])) + ((ay[4] + ay[5]) + (ay[6] + ay[7]))) * s;
    {  // z3
      float ss = fmaf(rx, rx, ry * ry);
      #pragma unroll
      for (int m = 32; m >= 1; m >>= 1) ss += __shfl_xor(ss, m);
      const float sc = 1.0f / fmaxf(sqrtf(ss), 1e-12f);
      *(unsigned*)(zbuf + (size_t)r * MD + 384 + lane * 2) =
          ((unsigned)f2bf(ry * sc) << 16) | f2bf(rx * sc);
    }
    // z0..z2 from u0..u2 rows
    unsigned v0 = *(const unsigned*)((const char*)x0 + ((unsigned)n << 8) + lc);
    unsigned v1 = *(const unsigned*)((const char*)x1 + ((unsigned)n << 8) + lc);
    unsigned v2 = *(const unsigned*)((const char*)x2 + ((unsigned)n << 8) + lc);
    unsigned vv[3] = {v0, v1, v2};
    #pragma unroll
    for (int q = 0; q < 3; ++q) {
      const float a = bflo(vv[q]), b = bfhi(vv[q]);
      float ss = fmaf(a, a, b * b);
      #pragma unroll
      for (int m = 32; m >= 1; m >>= 1) ss += __shfl_xor(ss, m);
      const float sc = 1.0f / fmaxf(sqrtf(ss), 1e-12f);
      *(unsigned*)(zbuf + (size_t)r * MD + q * DD + lane * 2) =
          ((unsigned)f2bf(b * sc) << 16) | f2bf(a * sc);
    }
  }
}

// ---- emb f32 -> u0 bf16 = dinv*emb; tail blocks convert W ----
__global__ __launch_bounds__(256) void k_conv_emb2(const float* __restrict__ emb,
                                                   const float* __restrict__ dinv,
                                                   unsigned short* __restrict__ x0,
                                                   const float* __restrict__ W,
                                                   unsigned short* __restrict__ Wbf) {
  if (blockIdx.x >= NN / 4) {  // W-conversion tail: 256 blocks x 256 float4
    const int i = (blockIdx.x - NN / 4) * 256 + threadIdx.x;
    if (i < MD * MD / 4) {
      float4 v = ((const float4*)W)[i];
      ushort4 o;
      o.x = f2bf(v.x); o.y = f2bf(v.y); o.z = f2bf(v.z); o.w = f2bf(v.w);
      ((ushort4*)Wbf)[i] = o;
    }
    return;
  }
  const int lane = threadIdx.x & 63;
  const int n = blockIdx.x * 4 + (threadIdx.x >> 6);
  const float2 v = ((const float2*)(emb + (size_t)n * DD))[lane];
  const float d = dinv[n];
  *(unsigned*)(x0 + (size_t)n * DD + lane * 2) =
      ((unsigned)f2bf(v.y * d) << 16) | f2bf(v.x * d);
}

// ---- MFMA GEMM, inline row lookup, XCD swizzle, LDS epilogue ----
// out[i][j] = sum_k zbuf[uidx[node(i)]][k] * W[j][k] + bias[j]
__global__ __launch_bounds__(256) void k_gemm(const unsigned short* __restrict__ zbuf,
                                              const int* __restrict__ sl,
                                              const int* __restrict__ rl,
                                              const int* __restrict__ uidx,
                                              const unsigned short* __restrict__ B,
                                              const float* __restrict__ bias,
                                              float* __restrict__ out) {
  __shared__ __align__(16) char smraw[20480];
  unsigned short (*As)[40] = (unsigned short(*)[40])smraw;            // 10240 B
  unsigned short (*Bs)[40] = (unsigned short(*)[40])(smraw + 10240);  // 10240 B
  float (*et)[132] = (float(*)[132])smraw;                            // 16896 B
  const int t = threadIdx.x;
  const int bid = blockIdx.x;
  const int xcd = bid & 7;
  const int j = bid >> 3;
  const int mt = xcd * 32 + (j >> 2);
  const int nt = j & 3;
  const int i0 = mt * 128, j0 = nt * 128;
  const int lane = t & 63, wid = t >> 6;
  const int wr = wid >> 1, wc = wid & 1;
  const int fr = lane & 15, kg = lane >> 4;
  const int srow = t >> 2, seg = t & 3;
  const int r0 = i0 + srow, r1 = r0 + 64;
  const int nd0 = (r0 < SEL) ? sl[r0] : rl[r0 - SEL];
  const int nd1 = (r1 < SEL) ? sl[r1] : rl[r1 - SEL];
  const unsigned short* pa0 = zbuf + (size_t)uidx[nd0] * MD + seg * 8;
  const unsigned short* pa1 = zbuf + (size_t)uidx[nd1] * MD + seg * 8;
  const unsigned short* pb0 = B + (size_t)(j0 + srow) * MD + seg * 8;
  const unsigned short* pb1 = B + (size_t)(j0 + srow + 64) * MD + seg * 8;
  f32x4 acc[4][4] = {};
  for (int k0 = 0; k0 < MD; k0 += 32) {
    *(float4*)(&As[srow][seg * 8]) = *(const float4*)(pa0 + k0);
    *(float4*)(&As[srow + 64][seg * 8]) = *(const float4*)(pa1 + k0);
    *(float4*)(&Bs[srow][seg * 8]) = *(const float4*)(pb0 + k0);
    *(float4*)(&Bs[srow + 64][seg * 8]) = *(const float4*)(pb1 + k0);
    __syncthreads();
    bf16x8 af[4], bfr[4];
    #pragma unroll
    for (int m = 0; m < 4; ++m)
      af[m] = *(const bf16x8*)(&As[wr * 64 + m * 16 + fr][kg * 8]);
    #pragma unroll
    for (int n = 0; n < 4; ++n)
      bfr[n] = *(const bf16x8*)(&Bs[wc * 64 + n * 16 + fr][kg * 8]);
    #pragma unroll
    for (int m = 0; m < 4; ++m)
      #pragma unroll
      for (int n = 0; n < 4; ++n)
        acc[m][n] = __builtin_amdgcn_mfma_f32_16x16x32_bf16(af[m], bfr[n], acc[m][n], 0, 0, 0);
    __syncthreads();
  }
  // epilogue: per m-chunk stage 32x128 f32 in LDS, write 512B-contiguous rows
  #pragma unroll
  for (int m = 0; m < 4; ++m) {
    __syncthreads();
    #pragma unroll
    for (int n = 0; n < 4; ++n)
      #pragma unroll
      for (int r = 0; r < 4; ++r)
        et[wr * 16 + kg * 4 + r][wc * 64 + n * 16 + fr] = acc[m][n][r];
    __syncthreads();
    #pragma unroll
    for (int w = 0; w < 4; ++w) {
      const int idx = w * 256 + t;
      const int lrow = idx >> 5, lc4 = idx & 31;
      const int grow = i0 + (lrow >> 4) * 64 + m * 16 + (lrow & 15);
      const int gcol = j0 + lc4 * 4;
      const float4 bv = *(const float4*)(bias + gcol);
      float4 o;
      o.x = et[lrow][lc4 * 4 + 0] + bv.x;
      o.y = et[lrow][lc4 * 4 + 1] + bv.y;
      o.z = et[lrow][lc4 * 4 + 2] + bv.z;
      o.w = et[lrow][lc4 * 4 + 3] + bv.w;
      *(float4*)(out + (size_t)grow * MD + gcol) = o;
    }
  }
}

extern "C" void kernel_launch(void* const* d_in, const int* in_sizes, int n_in,
                              void* d_out, int out_size, void* d_ws, size_t ws_size,
                              hipStream_t stream) {
  const float* emb = (const float*)d_in[0];
  const int* ei = (const int*)d_in[1];
  const int* esrc = ei;                     // edge_index[0]
  const int* edst = ei + NE;                // edge_index[1]
  const int* send = (const int*)d_in[2];
  const int* recv = (const int*)d_in[3];
  const float* W = (const float*)d_in[4];
  const float* bias = (const float*)d_in[5];
  float* out = (float*)d_out;

  char* ws = (char*)d_ws;
  size_t off = 0;
  auto take = [&](size_t b) {
    char* p = ws + off;
    off = (off + b + 1023) & ~(size_t)1023;
    return p;
  };
  int* zblk = (int*)take((size_t)(NBKT + 1 + NN) * 4);  // gcursor|lcnt|mark
  int* gcursor = zblk;                                  // becomes bcnt
  int* lcnt = zblk + NBKT;
  int* mark = zblk + NBKT + 1;
  int* uidx = (int*)take((size_t)NN * 4);   // only read at marked nodes
  float* dinv = (float*)take((size_t)NN * 4);
  int4* nodeinfo = (int4*)take((size_t)NN * 16);
  int* list = (int*)take((size_t)MROWS * 4);
  unsigned* ebuf = (unsigned*)take((size_t)NBKT * SEGCAP * 4);
  int* csr = (int*)take((size_t)NBKT * CSTRIDE * 4);
  unsigned short* x0 = (unsigned short*)take((size_t)(NN + 1) * DD * 2);
  unsigned short* x1 = (unsigned short*)take((size_t)(NN + 1) * DD * 2);
  unsigned short* x2 = (unsigned short*)take((size_t)(NN + 1) * DD * 2);
  unsigned short* zbuf = (unsigned short*)take((size_t)MROWS * MD * 2);
  unsigned short* Wbf = (unsigned short*)take((size_t)MD * MD * 2);
  (void)ws_size; (void)in_sizes; (void)n_in; (void)out_size;

  hipMemsetAsync(zblk, 0, (size_t)(NBKT + 1 + NN) * 4, stream);

  // ---- CSR build (2 kernels) + mark/compact fused as tail blocks ----
  k_binA_mark<<<NBINA + NMARK, 256, 0, stream>>>(esrc, edst, gcursor, ebuf,
                                                 send, recv, mark);
  k_degbinB<<<NBKT + NCOMP, 256, 0, stream>>>(ebuf, gcursor, dinv, nodeinfo, csr,
                                              x0, x1, x2, mark, list, lcnt, uidx);
  k_conv_emb2<<<NN / 4 + MD * MD / 4 / 256, 256, 0, stream>>>(emb, dinv, x0, W, Wbf);

  // 2 full feature-split layers; fused final layer + z-normalize
  k_aggs<<<4096, 256, 0, stream>>>(nodeinfo, csr, x0, x1);
  k_aggs<<<4096, 256, 0, stream>>>(nodeinfo, csr, x1, x2);
  k_agg3z<<<2048, 256, 0, stream>>>(nodeinfo, csr, x0, x1, x2, zbuf, list, lcnt);

  k_gemm<<<(MROWS / 128) * (MD / 128), 256, 0, stream>>>(zbuf, send, recv, uidx,
                                                         Wbf, bias, out);
}

// Round 16
// 250.190 us; speedup vs baseline: 1.0212x; 1.0212x over previous
//
#include <hip/hip_runtime.h>

#define NN 100000      // nodes
#define NE 1600000     // edges
#define DD 128         // input dim (elements per row)
#define MD 512         // mlp dim = 128*4
#define SEL 16384      // senders count
#define MROWS 32768    // senders + receivers rows
#define NBKT 196       // buckets of 512 nodes
#define TILE 4096      // edges per k_binA block
#define SEGCAP 16384   // per-bucket ebuf slot capacity
#define CSTRIDE 12288  // per-bucket padded CSR capacity (mean ~9984)
#define NBINA ((NE + TILE - 1) / TILE)   // 391
#define NMARK ((2 * SEL + 255) / 256)    // 128
#define NCOMP ((NN + 255) / 256)         // 391
#define AGGGRID 6256   // 782*8: waves/half = 12512; 50000/12512 = 3.996 iters

typedef __attribute__((ext_vector_type(8))) short bf16x8;
typedef __attribute__((ext_vector_type(4))) float f32x4;

__device__ __forceinline__ unsigned short f2bf(float f) {
  unsigned u = __float_as_uint(f);
  u += 0x7fff + ((u >> 16) & 1);   // round-to-nearest-even
  return (unsigned short)(u >> 16);
}
__device__ __forceinline__ float bflo(unsigned v) { return __uint_as_float(v << 16); }
__device__ __forceinline__ float bfhi(unsigned v) { return __uint_as_float(v & 0xffff0000u); }

// ---- bin edges into strided ebuf slices; tail blocks do the mark pass ----
__global__ __launch_bounds__(256) void k_binA_mark(const int* __restrict__ src,
                                                   const int* __restrict__ dst,
                                                   int* __restrict__ gcursor,
                                                   unsigned* __restrict__ ebuf,
                                                   const int* __restrict__ sl,
                                                   const int* __restrict__ rl,
                                                   int* __restrict__ mark) {
  if (blockIdx.x >= NBINA) {  // mark tail
    const int i = (blockIdx.x - NBINA) * 256 + threadIdx.x;
    if (i < SEL) mark[sl[i]] = 1;
    else if (i < 2 * SEL) mark[rl[i - SEL]] = 1;
    return;
  }
  __shared__ int hist[NBKT];
  __shared__ int base[NBKT];
  __shared__ int cnt2[NBKT];
  const int tid = threadIdx.x;
  const long e0 = (long)blockIdx.x * TILE;
  for (int i = tid; i < NBKT; i += 256) { hist[i] = 0; cnt2[i] = 0; }
  __syncthreads();
  unsigned pk[16]; int bk[16];
  #pragma unroll
  for (int k = 0; k < 16; ++k) {
    const long e = e0 + k * 256 + tid;
    bk[k] = -1;
    if (e < NE) {
      const int d = dst[e], s = src[e];
      bk[k] = d >> 9;
      pk[k] = ((unsigned)s << 9) | (unsigned)(d & 511);
      atomicAdd(&hist[bk[k]], 1);
    }
  }
  __syncthreads();
  for (int i = tid; i < NBKT; i += 256)
    base[i] = i * SEGCAP + atomicAdd(&gcursor[i], hist[i]);
  __syncthreads();
  #pragma unroll
  for (int k = 0; k < 16; ++k) {
    if (bk[k] >= 0) {
      const int lp = atomicAdd(&cnt2[bk[k]], 1);
      ebuf[base[bk[k]] + lp] = pk[k];
    }
  }
}

// ---- fused: per-bucket degree+dinv+scan + LDS scatter -> fixed-stride CSR ----
__global__ __launch_bounds__(256) void k_degbinB(const unsigned* __restrict__ ebuf,
                                                 const int* __restrict__ bcnt,
                                                 float* __restrict__ dinv,
                                                 int4* __restrict__ nodeinfo,
                                                 int* __restrict__ csr,
                                                 unsigned short* __restrict__ x0,
                                                 unsigned short* __restrict__ x1,
                                                 unsigned short* __restrict__ x2,
                                                 const int* __restrict__ mark,
                                                 int* __restrict__ list,
                                                 int* __restrict__ lcnt,
                                                 int* __restrict__ uidx) {
  if (blockIdx.x >= NBKT) {  // compact tail (mark completed last kernel)
    const int n = (blockIdx.x - NBKT) * 256 + threadIdx.x;
    if (n < NN && mark[n]) {
      const int p = atomicAdd(lcnt, 1);
      list[p] = n;
      uidx[n] = p;
    }
    return;
  }
  __shared__ int ld[512];
  __shared__ int ps[256];
  __shared__ int rs[512];
  __shared__ int cnt[512];
  __shared__ int seg[CSTRIDE];
  const int b = blockIdx.x;
  const int n0 = b << 9;
  const int nn = min(512, NN - n0);
  const int tid = threadIdx.x;
  for (int i = tid; i < 512; i += 256) ld[i] = 0;
  __syncthreads();
  const int s0 = b * SEGCAP;
  const int c = bcnt[b];
  for (int i = tid; i < c; i += 256) atomicAdd(&ld[ebuf[s0 + i] & 511], 1);
  __syncthreads();
  const int d0 = (tid * 2 < nn) ? ld[tid * 2] : 0;
  const int d1 = (tid * 2 + 1 < nn) ? ld[tid * 2 + 1] : 0;
  const int p0 = (d0 + 7) & ~7, p1 = (d1 + 7) & ~7;
  ps[tid] = p0 + p1;
  __syncthreads();
  for (int o = 1; o < 256; o <<= 1) {
    int t2 = (tid >= o) ? ps[tid - o] : 0;
    __syncthreads();
    ps[tid] += t2;
    __syncthreads();
  }
  const int exbase = ps[tid] - (p0 + p1);
  const int cb = b * CSTRIDE;
  if (tid * 2 < nn) {
    const float dv = rsqrtf(fmaxf((float)d0, 1.f));
    dinv[n0 + tid * 2] = dv;
    rs[tid * 2] = exbase;
    nodeinfo[n0 + tid * 2] = make_int4(cb + exbase, p0, __float_as_int(dv * dv), 0);
  }
  if (tid * 2 + 1 < nn) {
    const float dv = rsqrtf(fmaxf((float)d1, 1.f));
    dinv[n0 + tid * 2 + 1] = dv;
    rs[tid * 2 + 1] = exbase + p0;
    nodeinfo[n0 + tid * 2 + 1] = make_int4(cb + exbase + p0, p1, __float_as_int(dv * dv), 0);
  }
  const int padtot = ps[255];
  for (int i = tid; i < nn; i += 256) cnt[i] = 0;
  for (int i = tid; i < padtot; i += 256) seg[i] = NN << 8;  // sentinel pad
  __syncthreads();
  for (int i = tid; i < c; i += 256) {
    const unsigned e = ebuf[s0 + i];
    const int dl = e & 511;
    const int pos = rs[dl] + atomicAdd(&cnt[dl], 1);
    seg[pos] = (int)((e >> 9) << 8);   // byte offset of src row (256 B rows)
  }
  __syncthreads();
  for (int i = tid; i < padtot; i += 256) csr[cb + i] = seg[i];
  if (b == 0 && tid < 64) {  // zero the sentinel row NN of each x buffer
    ((unsigned*)(x0 + (size_t)NN * DD))[tid] = 0u;
    ((unsigned*)(x1 + (size_t)NN * DD))[tid] = 0u;
    ((unsigned*)(x2 + (size_t)NN * DD))[tid] = 0u;
  }
}

// ---- feature-split aggregation: wave = 2 (node,half) items, pipelined ----
// Half h handled only by blocks with (bid&7)>>2 == h (XCD-affinity heuristic).
// nodeinfo prefetched one iteration ahead; csr quads double-buffered.
// Grid chosen so waves/half (=2*gridDim.x) divides the 50000 pair-items
// nearly exactly (tail-balance).
__global__ __launch_bounds__(256) void k_aggs(const int4* __restrict__ nodeinfo,
                                              const int* __restrict__ csr,
                                              const unsigned short* __restrict__ xin,
                                              unsigned short* __restrict__ xout) {
  const int lane = threadIdx.x & 63;
  const int hi = lane >> 5, l5 = lane & 31;
  const int bid = blockIdx.x;
  const int xcd = bid & 7;
  const int h = xcd >> 2;                       // feature half
  const int g = (bid >> 3) * 4 + (xcd & 3);     // block index within half-group
  const int wvh = g * 4 + (threadIdx.x >> 6);   // wave index within half-group
  const int stride = gridDim.x * 2;             // waves per half-group
  const char* xb = (const char*)xin;
  const unsigned lc = (unsigned)(h * 128 + l5 * 4);  // byte offset within row
  int p = wvh;
  if (2 * p >= NN) return;
  int4 ni = nodeinfo[min(2 * p + hi, NN - 1)];
  for (; 2 * p < NN; p += stride) {
    const int idx = 2 * p + hi;
    const bool act = idx < NN;
    const int4 cur = ni;
    const int pn = p + stride;
    if (2 * pn < NN) ni = nodeinfo[min(2 * pn + hi, NN - 1)];  // prefetch
    const int start = cur.x;
    const int cntp = act ? cur.y : 0;
    float ax[8], ay[8];
    #pragma unroll
    for (int u = 0; u < 8; ++u) { ax[u] = 0.f; ay[u] = 0.f; }
    int4 e0, e1;
    if (cntp > 0) {
      e0 = *(const int4*)(csr + start);
      e1 = *(const int4*)(csr + start + 4);
    }
    for (int j = 0; j < cntp; j += 8) {
      const int4 f0 = e0, f1 = e1;
      if (j + 8 < cntp) {  // double-buffer next csr quad pair
        e0 = *(const int4*)(csr + start + j + 8);
        e1 = *(const int4*)(csr + start + j + 12);
      }
      unsigned v[8];
      v[0] = *(const unsigned*)(xb + ((unsigned)f0.x + lc));
      v[1] = *(const unsigned*)(xb + ((unsigned)f0.y + lc));
      v[2] = *(const unsigned*)(xb + ((unsigned)f0.z + lc));
      v[3] = *(const unsigned*)(xb + ((unsigned)f0.w + lc));
      v[4] = *(const unsigned*)(xb + ((unsigned)f1.x + lc));
      v[5] = *(const unsigned*)(xb + ((unsigned)f1.y + lc));
      v[6] = *(const unsigned*)(xb + ((unsigned)f1.z + lc));
      v[7] = *(const unsigned*)(xb + ((unsigned)f1.w + lc));
      #pragma unroll
      for (int u = 0; u < 8; ++u) { ax[u] += bflo(v[u]); ay[u] += bfhi(v[u]); }
    }
    if (act) {
      const float s = __int_as_float(cur.z);   // dinv^2
      const float rx = (((ax[0] + ax[1]) + (ax[2] + ax[3])) + ((ax[4] + ax[5]) + (ax[6] + ax[7]))) * s;
      const float ry = (((ay[0] + ay[1]) + (ay[2] + ay[3])) + ((ay[4] + ay[5]) + (ay[6] + ay[7]))) * s;
      *(unsigned*)((char*)xout + ((unsigned)idx << 8) + lc) =
          ((unsigned)f2bf(ry) << 16) | f2bf(rx);
    }
  }
}

// ---- layer-3 aggregation (listed nodes, full row) + all four z-slices ----
__global__ __launch_bounds__(256) void k_agg3z(const int4* __restrict__ nodeinfo,
                                               const int* __restrict__ csr,
                                               const unsigned short* __restrict__ x0,
                                               const unsigned short* __restrict__ x1,
                                               const unsigned short* __restrict__ x2,
                                               unsigned short* __restrict__ zbuf,
                                               const int* __restrict__ list,
                                               const int* __restrict__ lcnt) {
  const int lane = threadIdx.x & 63;
  const int wv = (blockIdx.x * blockDim.x + threadIdx.x) >> 6;
  const int nw = (gridDim.x * blockDim.x) >> 6;
  const int cl = *lcnt;
  const char* xb2 = (const char*)x2;
  const unsigned lc = (unsigned)(lane * 4);
  int r = wv;
  if (r >= cl) return;
  int nln = list[r];
  for (; r < cl; r += nw) {
    const int n = nln;
    const int rn = r + nw;
    if (rn < cl) nln = list[rn];  // prefetch next list entry
    const int4 ni = nodeinfo[n];
    const int start = ni.x;
    const int cntp = ni.y;
    float ax[8], ay[8];
    #pragma unroll
    for (int u = 0; u < 8; ++u) { ax[u] = 0.f; ay[u] = 0.f; }
    int4 e0 = *(const int4*)(csr + start);
    int4 e1 = *(const int4*)(csr + start + 4);
    for (int j = 0; j < cntp; j += 8) {
      const int4 f0 = e0, f1 = e1;
      if (j + 8 < cntp) {
        e0 = *(const int4*)(csr + start + j + 8);
        e1 = *(const int4*)(csr + start + j + 12);
      }
      unsigned v[8];
      v[0] = *(const unsigned*)(xb2 + ((unsigned)f0.x + lc));
      v[1] = *(const unsigned*)(xb2 + ((unsigned)f0.y + lc));
      v[2] = *(const unsigned*)(xb2 + ((unsigned)f0.z + lc));
      v[3] = *(const unsigned*)(xb2 + ((unsigned)f0.w + lc));
      v[4] = *(const unsigned*)(xb2 + ((unsigned)f1.x + lc));
      v[5] = *(const unsigned*)(xb2 + ((unsigned)f1.y + lc));
      v[6] = *(const unsigned*)(xb2 + ((unsigned)f1.z + lc));
      v[7] = *(const unsigned*)(xb2 + ((unsigned)f1.w + lc));
      #pragma unroll
      for (int u = 0; u < 8; ++u) { ax[u] += bflo(v[u]); ay[u] += bfhi(v[u]); }
    }
    const float s = __int_as_float(ni.z);
    const float rx = (((ax[0] + ax[1]) + (ax[2] + ax[3])) + ((ax[4] + ax[5]) + (ax[6] + ax[7]))) * s;
    const float ry = (((ay[0] + ay[1]) + (ay[2] + ay[3])) + ((ay[4] + ay[5]) + (ay[6] + ay[7]))) * s;
    {  // z3
      float ss = fmaf(rx, rx, ry * ry);
      #pragma unroll
      for (int m = 32; m >= 1; m >>= 1) ss += __shfl_xor(ss, m);
      const float sc = 1.0f / fmaxf(sqrtf(ss), 1e-12f);
      *(unsigned*)(zbuf + (size_t)r * MD + 384 + lane * 2) =
          ((unsigned)f2bf(ry * sc) << 16) | f2bf(rx * sc);
    }
    // z0..z2 from u0..u2 rows
    unsigned v0 = *(const unsigned*)((const char*)x0 + ((unsigned)n << 8) + lc);
    unsigned v1 = *(const unsigned*)((const char*)x1 + ((unsigned)n << 8) + lc);
    unsigned v2 = *(const unsigned*)((const char*)x2 + ((unsigned)n << 8) + lc);
    unsigned vv[3] = {v0, v1, v2};
    #pragma unroll
    for (int q = 0; q < 3; ++q) {
      const float a = bflo(vv[q]), b = bfhi(vv[q]);
      float ss = fmaf(a, a, b * b);
      #pragma unroll
      for (int m = 32; m >= 1; m >>= 1) ss += __shfl_xor(ss, m);
      const float sc = 1.0f / fmaxf(sqrtf(ss), 1e-12f);
      *(unsigned*)(zbuf + (size_t)r * MD + q * DD + lane * 2) =
          ((unsigned)f2bf(b * sc) << 16) | f2bf(a * sc);
    }
  }
}

// ---- emb f32 -> u0 bf16 = dinv*emb; tail blocks convert W ----
__global__ __launch_bounds__(256) void k_conv_emb2(const float* __restrict__ emb,
                                                   const float* __restrict__ dinv,
                                                   unsigned short* __restrict__ x0,
                                                   const float* __restrict__ W,
                                                   unsigned short* __restrict__ Wbf) {
  if (blockIdx.x >= NN / 4) {  // W-conversion tail: 256 blocks x 256 float4
    const int i = (blockIdx.x - NN / 4) * 256 + threadIdx.x;
    if (i < MD * MD / 4) {
      float4 v = ((const float4*)W)[i];
      ushort4 o;
      o.x = f2bf(v.x); o.y = f2bf(v.y); o.z = f2bf(v.z); o.w = f2bf(v.w);
      ((ushort4*)Wbf)[i] = o;
    }
    return;
  }
  const int lane = threadIdx.x & 63;
  const int n = blockIdx.x * 4 + (threadIdx.x >> 6);
  const float2 v = ((const float2*)(emb + (size_t)n * DD))[lane];
  const float d = dinv[n];
  *(unsigned*)(x0 + (size_t)n * DD + lane * 2) =
      ((unsigned)f2bf(v.y * d) << 16) | f2bf(v.x * d);
}

// ---- MFMA GEMM, inline row lookup, XCD swizzle, LDS epilogue ----
// out[i][j] = sum_k zbuf[uidx[node(i)]][k] * W[j][k] + bias[j]
__global__ __launch_bounds__(256) void k_gemm(const unsigned short* __restrict__ zbuf,
                                              const int* __restrict__ sl,
                                              const int* __restrict__ rl,
                                              const int* __restrict__ uidx,
                                              const unsigned short* __restrict__ B,
                                              const float* __restrict__ bias,
                                              float* __restrict__ out) {
  __shared__ __align__(16) char smraw[20480];
  unsigned short (*As)[40] = (unsigned short(*)[40])smraw;            // 10240 B
  unsigned short (*Bs)[40] = (unsigned short(*)[40])(smraw + 10240);  // 10240 B
  float (*et)[132] = (float(*)[132])smraw;                            // 16896 B
  const int t = threadIdx.x;
  const int bid = blockIdx.x;
  const int xcd = bid & 7;
  const int j = bid >> 3;
  const int mt = xcd * 32 + (j >> 2);
  const int nt = j & 3;
  const int i0 = mt * 128, j0 = nt * 128;
  const int lane = t & 63, wid = t >> 6;
  const int wr = wid >> 1, wc = wid & 1;
  const int fr = lane & 15, kg = lane >> 4;
  const int srow = t >> 2, seg = t & 3;
  const int r0 = i0 + srow, r1 = r0 + 64;
  const int nd0 = (r0 < SEL) ? sl[r0] : rl[r0 - SEL];
  const int nd1 = (r1 < SEL) ? sl[r1] : rl[r1 - SEL];
  const unsigned short* pa0 = zbuf + (size_t)uidx[nd0] * MD + seg * 8;
  const unsigned short* pa1 = zbuf + (size_t)uidx[nd1] * MD + seg * 8;
  const unsigned short* pb0 = B + (size_t)(j0 + srow) * MD + seg * 8;
  const unsigned short* pb1 = B + (size_t)(j0 + srow + 64) * MD + seg * 8;
  f32x4 acc[4][4] = {};
  for (int k0 = 0; k0 < MD; k0 += 32) {
    *(float4*)(&As[srow][seg * 8]) = *(const float4*)(pa0 + k0);
    *(float4*)(&As[srow + 64][seg * 8]) = *(const float4*)(pa1 + k0);
    *(float4*)(&Bs[srow][seg * 8]) = *(const float4*)(pb0 + k0);
    *(float4*)(&Bs[srow + 64][seg * 8]) = *(const float4*)(pb1 + k0);
    __syncthreads();
    bf16x8 af[4], bfr[4];
    #pragma unroll
    for (int m = 0; m < 4; ++m)
      af[m] = *(const bf16x8*)(&As[wr * 64 + m * 16 + fr][kg * 8]);
    #pragma unroll
    for (int n = 0; n < 4; ++n)
      bfr[n] = *(const bf16x8*)(&Bs[wc * 64 + n * 16 + fr][kg * 8]);
    #pragma unroll
    for (int m = 0; m < 4; ++m)
      #pragma unroll
      for (int n = 0; n < 4; ++n)
        acc[m][n] = __builtin_amdgcn_mfma_f32_16x16x32_bf16(af[m], bfr[n], acc[m][n], 0, 0, 0);
    __syncthreads();
  }
  // epilogue: per m-chunk stage 32x128 f32 in LDS, write 512B-contiguous rows
  #pragma unroll
  for (int m = 0; m < 4; ++m) {
    __syncthreads();
    #pragma unroll
    for (int n = 0; n < 4; ++n)
      #pragma unroll
      for (int r = 0; r < 4; ++r)
        et[wr * 16 + kg * 4 + r][wc * 64 + n * 16 + fr] = acc[m][n][r];
    __syncthreads();
    #pragma unroll
    for (int w = 0; w < 4; ++w) {
      const int idx = w * 256 + t;
      const int lrow = idx >> 5, lc4 = idx & 31;
      const int grow = i0 + (lrow >> 4) * 64 + m * 16 + (lrow & 15);
      const int gcol = j0 + lc4 * 4;
      const float4 bv = *(const float4*)(bias + gcol);
      float4 o;
      o.x = et[lrow][lc4 * 4 + 0] + bv.x;
      o.y = et[lrow][lc4 * 4 + 1] + bv.y;
      o.z = et[lrow][lc4 * 4 + 2] + bv.z;
      o.w = et[lrow][lc4 * 4 + 3] + bv.w;
      *(float4*)(out + (size_t)grow * MD + gcol) = o;
    }
  }
}

extern "C" void kernel_launch(void* const* d_in, const int* in_sizes, int n_in,
                              void* d_out, int out_size, void* d_ws, size_t ws_size,
                              hipStream_t stream) {
  const float* emb = (const float*)d_in[0];
  const int* ei = (const int*)d_in[1];
  const int* esrc = ei;                     // edge_index[0]
  const int* edst = ei + NE;                // edge_index[1]
  const int* send = (const int*)d_in[2];
  const int* recv = (const int*)d_in[3];
  const float* W = (const float*)d_in[4];
  const float* bias = (const float*)d_in[5];
  float* out = (float*)d_out;

  char* ws = (char*)d_ws;
  size_t off = 0;
  auto take = [&](size_t b) {
    char* p = ws + off;
    off = (off + b + 1023) & ~(size_t)1023;
    return p;
  };
  int* zblk = (int*)take((size_t)(NBKT + 1 + NN) * 4);  // gcursor|lcnt|mark
  int* gcursor = zblk;                                  // becomes bcnt
  int* lcnt = zblk + NBKT;
  int* mark = zblk + NBKT + 1;
  int* uidx = (int*)take((size_t)NN * 4);   // only read at marked nodes
  float* dinv = (float*)take((size_t)NN * 4);
  int4* nodeinfo = (int4*)take((size_t)NN * 16);
  int* list = (int*)take((size_t)MROWS * 4);
  unsigned* ebuf = (unsigned*)take((size_t)NBKT * SEGCAP * 4);
  int* csr = (int*)take((size_t)NBKT * CSTRIDE * 4);
  unsigned short* x0 = (unsigned short*)take((size_t)(NN + 1) * DD * 2);
  unsigned short* x1 = (unsigned short*)take((size_t)(NN + 1) * DD * 2);
  unsigned short* x2 = (unsigned short*)take((size_t)(NN + 1) * DD * 2);
  unsigned short* zbuf = (unsigned short*)take((size_t)MROWS * MD * 2);
  unsigned short* Wbf = (unsigned short*)take((size_t)MD * MD * 2);
  (void)ws_size; (void)in_sizes; (void)n_in; (void)out_size;

  hipMemsetAsync(zblk, 0, (size_t)(NBKT + 1 + NN) * 4, stream);

  // ---- CSR build (2 kernels) + mark/compact fused as tail blocks ----
  k_binA_mark<<<NBINA + NMARK, 256, 0, stream>>>(esrc, edst, gcursor, ebuf,
                                                 send, recv, mark);
  k_degbinB<<<NBKT + NCOMP, 256, 0, stream>>>(ebuf, gcursor, dinv, nodeinfo, csr,
                                              x0, x1, x2, mark, list, lcnt, uidx);
  k_conv_emb2<<<NN / 4 + MD * MD / 4 / 256, 256, 0, stream>>>(emb, dinv, x0, W, Wbf);

  // 2 full feature-split layers; fused final layer + z-normalize
  k_aggs<<<AGGGRID, 256, 0, stream>>>(nodeinfo, csr, x0, x1);
  k_aggs<<<AGGGRID, 256, 0, stream>>>(nodeinfo, csr, x1, x2);
  k_agg3z<<<1792, 256, 0, stream>>>(nodeinfo, csr, x0, x1, x2, zbuf, list, lcnt);

  k_gemm<<<(MROWS / 128) * (MD / 128), 256, 0, stream>>>(zbuf, send, recv, uidx,
                                                         Wbf, bias, out);
}